// Round 4
// baseline (233.266 us; speedup 1.0000x reference)
//
#include <hip/hip_runtime.h>

// out[m,k] = D*(w-1)*rowsum(t[m]) broadcast over k (K = D = 2048).
// Memory-bound: 128 MiB read + 128 MiB write. Mixed-stream HBM floor ~43 us;
// but harness restores d_in (128 MiB) right before every timed launch, so the
// tensor is likely Infinity-Cache-resident (256 MiB LLC). Round 3's
// nontemporal hints defeat L3 retention -> dropped here (that is the only
// change vs round 3). Wave-per-row, no LDS, no barriers.

#define M_ROWS 16384
#define D_COLS 2048
#define F4_PER_ROW (D_COLS / 4)   // 512
#define WAVES_PER_BLOCK 4
#define BLOCK_SIZE (WAVES_PER_BLOCK * 64)

typedef float vf4 __attribute__((ext_vector_type(4)));

__global__ __launch_bounds__(BLOCK_SIZE)
void perm_equiv_wave_row(const float* __restrict__ t,
                         const float* __restrict__ w,
                         float* __restrict__ out) {
    const int lane = threadIdx.x & 63;
    const int row  = blockIdx.x * WAVES_PER_BLOCK + (threadIdx.x >> 6);

    const vf4* trow = reinterpret_cast<const vf4*>(t) + (size_t)row * F4_PER_ROW;

    // 8 coalesced 16B loads: lane i touches f4 index j*64 + i.
    vf4 v[8];
    #pragma unroll
    for (int j = 0; j < 8; ++j)
        v[j] = trow[j * 64 + lane];

    float s = 0.0f;
    #pragma unroll
    for (int j = 0; j < 8; ++j)
        s += (v[j].x + v[j].y) + (v[j].z + v[j].w);

    // wave-64 butterfly: every lane ends with the full row sum.
    #pragma unroll
    for (int m = 32; m > 0; m >>= 1)
        s += __shfl_xor(s, m, 64);

    const float val = (float)D_COLS * (w[0] - 1.0f) * s;
    vf4 v4;
    v4.x = val; v4.y = val; v4.z = val; v4.w = val;

    vf4* orow = reinterpret_cast<vf4*>(out) + (size_t)row * F4_PER_ROW;
    #pragma unroll
    for (int j = 0; j < 8; ++j)
        orow[j * 64 + lane] = v4;
}

extern "C" void kernel_launch(void* const* d_in, const int* in_sizes, int n_in,
                              void* d_out, int out_size, void* d_ws, size_t ws_size,
                              hipStream_t stream) {
    const float* t = (const float*)d_in[0];
    const float* w = (const float*)d_in[1];
    float* out = (float*)d_out;
    perm_equiv_wave_row<<<M_ROWS / WAVES_PER_BLOCK, BLOCK_SIZE, 0, stream>>>(t, w, out);
}

// Round 5
// 230.419 us; speedup vs baseline: 1.0124x; 1.0124x over previous
//
#include <hip/hip_runtime.h>

// out[m,k] = D*(w-1)*rowsum(t[m]) broadcast over k (K = D = 2048).
//
// Round-4 evidence: fused read+write kernel runs at 31% of HBM peak (82 us),
// while the harness's pure-write fills run at 85% (6.6-6.8 TB/s). Mixed
// streams are the limiter, not BW itself. So: split into two single-direction
// phases via a 64 KB rowsum scratch in d_ws.
//   k1: pure read (L3-warm input; round 4 showed 50% fetch absorption)
//   k2: pure write at fill-rate, reading only the 64 KB rowsum array.

#define M_ROWS 16384
#define D_COLS 2048
#define F4_PER_ROW (D_COLS / 4)   // 512
#define WAVES_PER_BLOCK 4
#define BLOCK_SIZE (WAVES_PER_BLOCK * 64)

typedef float vf4 __attribute__((ext_vector_type(4)));

// Phase 1: rowsum[m] = sum_k t[m,k]. Pure-read stream + 4 B/row store.
__global__ __launch_bounds__(BLOCK_SIZE)
void k_rowsum(const float* __restrict__ t, float* __restrict__ rowsum) {
    const int lane = threadIdx.x & 63;
    const int row  = blockIdx.x * WAVES_PER_BLOCK + (threadIdx.x >> 6);

    const vf4* trow = reinterpret_cast<const vf4*>(t) + (size_t)row * F4_PER_ROW;

    vf4 v[8];
    #pragma unroll
    for (int j = 0; j < 8; ++j)
        v[j] = trow[j * 64 + lane];

    float s = 0.0f;
    #pragma unroll
    for (int j = 0; j < 8; ++j)
        s += (v[j].x + v[j].y) + (v[j].z + v[j].w);

    #pragma unroll
    for (int m = 32; m > 0; m >>= 1)
        s += __shfl_xor(s, m, 64);

    if (lane == 0) rowsum[row] = s;
}

// Phase 2: out[m,:] = D*(w-1)*rowsum[m]. Pure-write stream (fill-like).
__global__ __launch_bounds__(BLOCK_SIZE)
void k_bcast(const float* __restrict__ rowsum, const float* __restrict__ w,
             float* __restrict__ out) {
    const int lane = threadIdx.x & 63;
    const int row  = blockIdx.x * WAVES_PER_BLOCK + (threadIdx.x >> 6);

    const float val = (float)D_COLS * (w[0] - 1.0f) * rowsum[row];
    vf4 v4;
    v4.x = val; v4.y = val; v4.z = val; v4.w = val;

    vf4* orow = reinterpret_cast<vf4*>(out) + (size_t)row * F4_PER_ROW;
    #pragma unroll
    for (int j = 0; j < 8; ++j)
        orow[j * 64 + lane] = v4;
}

extern "C" void kernel_launch(void* const* d_in, const int* in_sizes, int n_in,
                              void* d_out, int out_size, void* d_ws, size_t ws_size,
                              hipStream_t stream) {
    const float* t = (const float*)d_in[0];
    const float* w = (const float*)d_in[1];
    float* out = (float*)d_out;
    float* rowsum = (float*)d_ws;   // 16384 floats = 64 KB

    k_rowsum<<<M_ROWS / WAVES_PER_BLOCK, BLOCK_SIZE, 0, stream>>>(t, rowsum);
    k_bcast <<<M_ROWS / WAVES_PER_BLOCK, BLOCK_SIZE, 0, stream>>>(rowsum, w, out);
}

// Round 6
// 229.404 us; speedup vs baseline: 1.0168x; 1.0044x over previous
//
#include <hip/hip_runtime.h>

// out[m,k] = D*(w-1)*rowsum(t[m]) broadcast over k (K = D = 2048).
//
// Evidence so far (rounds 3-5): writes sustain 6.6-6.8 TB/s (fill-like),
// reads crawl at ~2.4 TB/s. Read phase is outstanding-miss-bound: the old
// wave-per-row shape drains vmcnt(0) per row. Fix: 4 rows/wave with
// register double-buffer lookahead (wait at vmcnt(8), pipe never drains).
// Write phase: nontemporal stores (proven +11us in round 3 vs plain).

#define M_ROWS 16384
#define D_COLS 2048
#define F4_PER_ROW (D_COLS / 4)   // 512
#define WAVES_PER_BLOCK 4
#define BLOCK_SIZE (WAVES_PER_BLOCK * 64)
#define ROWS_PER_WAVE 4

typedef float vf4 __attribute__((ext_vector_type(4)));

// Phase 1: rowsum[m] = sum_k t[m,k]. Pure-read, software-pipelined.
__global__ __launch_bounds__(BLOCK_SIZE)
void k_rowsum(const float* __restrict__ t, float* __restrict__ rowsum) {
    const int lane  = threadIdx.x & 63;
    const int gwave = blockIdx.x * WAVES_PER_BLOCK + (threadIdx.x >> 6);
    const int row0  = gwave * ROWS_PER_WAVE;

    const vf4* base = reinterpret_cast<const vf4*>(t) + (size_t)row0 * F4_PER_ROW;

    // prime: row 0's 8 loads
    vf4 cur[8];
    #pragma unroll
    for (int j = 0; j < 8; ++j)
        cur[j] = base[j * 64 + lane];

    #pragma unroll
    for (int r = 0; r < ROWS_PER_WAVE; ++r) {
        // issue next row's loads BEFORE reducing current row -> wave waits
        // at vmcnt(8), read pipe stays full.
        vf4 nxt[8];
        if (r + 1 < ROWS_PER_WAVE) {
            const vf4* q = base + (size_t)(r + 1) * F4_PER_ROW;
            #pragma unroll
            for (int j = 0; j < 8; ++j)
                nxt[j] = q[j * 64 + lane];
        }

        float s = 0.0f;
        #pragma unroll
        for (int j = 0; j < 8; ++j)
            s += (cur[j].x + cur[j].y) + (cur[j].z + cur[j].w);

        #pragma unroll
        for (int m = 32; m > 0; m >>= 1)
            s += __shfl_xor(s, m, 64);

        if (lane == 0) rowsum[row0 + r] = s;

        if (r + 1 < ROWS_PER_WAVE) {
            #pragma unroll
            for (int j = 0; j < 8; ++j)
                cur[j] = nxt[j];
        }
    }
}

// Phase 2: out[m,:] = D*(w-1)*rowsum[m]. Pure-write stream, nontemporal.
__global__ __launch_bounds__(BLOCK_SIZE)
void k_bcast(const float* __restrict__ rowsum, const float* __restrict__ w,
             float* __restrict__ out) {
    const int lane = threadIdx.x & 63;
    const int row  = blockIdx.x * WAVES_PER_BLOCK + (threadIdx.x >> 6);

    const float val = (float)D_COLS * (w[0] - 1.0f) * rowsum[row];
    vf4 v4;
    v4.x = val; v4.y = val; v4.z = val; v4.w = val;

    vf4* orow = reinterpret_cast<vf4*>(out) + (size_t)row * F4_PER_ROW;
    #pragma unroll
    for (int j = 0; j < 8; ++j)
        __builtin_nontemporal_store(v4, orow + j * 64 + lane);
}

extern "C" void kernel_launch(void* const* d_in, const int* in_sizes, int n_in,
                              void* d_out, int out_size, void* d_ws, size_t ws_size,
                              hipStream_t stream) {
    const float* t = (const float*)d_in[0];
    const float* w = (const float*)d_in[1];
    float* out = (float*)d_out;
    float* rowsum = (float*)d_ws;   // 16384 floats = 64 KB

    k_rowsum<<<M_ROWS / (WAVES_PER_BLOCK * ROWS_PER_WAVE), BLOCK_SIZE, 0, stream>>>(t, rowsum);
    k_bcast <<<M_ROWS / WAVES_PER_BLOCK, BLOCK_SIZE, 0, stream>>>(rowsum, w, out);
}

// Round 7
// 222.651 us; speedup vs baseline: 1.0477x; 1.0303x over previous
//
#include <hip/hip_runtime.h>

// out[m,k] = D*(w-1)*rowsum(t[m]) broadcast over k (K = D = 2048).
//
// Copy-shaped traffic: 128 MiB read + 128 MiB write; m13 copy ceiling
// 6.29 TB/s aggregate -> ~43 us floor. Best so far: fused + NT both ways
// (R3, ~71 us). R5/R6 split was worse; R6 showed read-only pipelining is
// neutral. This round: keep the R3 winner, add persistent grid-stride
// waves (no per-row block launch/drain) + 2-deep register pipeline so the
// wave waits at vmcnt(8) instead of vmcnt(0) while NT stores overlap the
// next row's loads. NT loads kept: R3(NT) beat R4(plain) 71 vs 82 even
// with L3 absorbing half the plain-load fetches.

#define M_ROWS 16384
#define D_COLS 2048
#define F4_PER_ROW (D_COLS / 4)   // 512
#define WAVES_PER_BLOCK 4
#define BLOCK_SIZE (WAVES_PER_BLOCK * 64)
#define GRID_BLOCKS 1024          // 4 blocks/CU, 16 waves/CU resident
#define TOTAL_WAVES (GRID_BLOCKS * WAVES_PER_BLOCK)       // 4096
#define ROWS_PER_WAVE (M_ROWS / TOTAL_WAVES)              // 4

typedef float vf4 __attribute__((ext_vector_type(4)));

__global__ __launch_bounds__(BLOCK_SIZE)
void perm_equiv_persist(const float* __restrict__ t,
                        const float* __restrict__ w,
                        float* __restrict__ out) {
    const int lane  = threadIdx.x & 63;
    const int gwave = blockIdx.x * WAVES_PER_BLOCK + (threadIdx.x >> 6);

    const float scale = (float)D_COLS * (w[0] - 1.0f);

    // Grid-stride over rows: wave g handles rows g, g+4096, g+8192, g+12288.
    // Consecutive waves touch consecutive rows -> global stream stays dense.
    const vf4* tin  = reinterpret_cast<const vf4*>(t);
    vf4*       oput = reinterpret_cast<vf4*>(out);

    // prologue: prime row 0's loads
    const vf4* p0 = tin + (size_t)gwave * F4_PER_ROW;
    vf4 cur[8];
    #pragma unroll
    for (int j = 0; j < 8; ++j)
        cur[j] = __builtin_nontemporal_load(p0 + j * 64 + lane);

    #pragma unroll
    for (int r = 0; r < ROWS_PER_WAVE; ++r) {
        const int row = gwave + r * TOTAL_WAVES;

        // issue next row's loads BEFORE consuming current row
        vf4 nxt[8];
        if (r + 1 < ROWS_PER_WAVE) {
            const vf4* pn = tin + (size_t)(row + TOTAL_WAVES) * F4_PER_ROW;
            #pragma unroll
            for (int j = 0; j < 8; ++j)
                nxt[j] = __builtin_nontemporal_load(pn + j * 64 + lane);
        }

        float s = 0.0f;
        #pragma unroll
        for (int j = 0; j < 8; ++j)
            s += (cur[j].x + cur[j].y) + (cur[j].z + cur[j].w);

        // wave-64 butterfly: every lane ends with the full row sum.
        #pragma unroll
        for (int m = 32; m > 0; m >>= 1)
            s += __shfl_xor(s, m, 64);

        const float val = scale * s;
        vf4 v4;
        v4.x = val; v4.y = val; v4.z = val; v4.w = val;

        vf4* orow = oput + (size_t)row * F4_PER_ROW;
        #pragma unroll
        for (int j = 0; j < 8; ++j)
            __builtin_nontemporal_store(v4, orow + j * 64 + lane);

        if (r + 1 < ROWS_PER_WAVE) {
            #pragma unroll
            for (int j = 0; j < 8; ++j)
                cur[j] = nxt[j];
        }
    }
}

extern "C" void kernel_launch(void* const* d_in, const int* in_sizes, int n_in,
                              void* d_out, int out_size, void* d_ws, size_t ws_size,
                              hipStream_t stream) {
    const float* t = (const float*)d_in[0];
    const float* w = (const float*)d_in[1];
    float* out = (float*)d_out;
    perm_equiv_persist<<<GRID_BLOCKS, BLOCK_SIZE, 0, stream>>>(t, w, out);
}